// Round 1
// baseline (511.696 us; speedup 1.0000x reference)
//
#include <hip/hip_runtime.h>

#define G      1024
#define NNODES 65536
#define NEDGES 262144
#define D      256
#define DIN    768
#define DHID   512
#define DOUT   256

constexpr int EDGE_CHUNK  = 128;                    // rows per block (4 waves -> 32 rows/wave)
constexpr int NODE_CHUNK  = 64;                     // 16 rows/wave
constexpr int EDGE_BLOCKS = NEDGES / EDGE_CHUNK;    // 2048
constexpr int NODE_BLOCKS = NNODES / NODE_CHUNK;    // 1024
constexpr int COPY_BLOCKS = (G * D / 4) / 256;      // 256 (float4 copy of globals)

// Sorted-segment sum: each wave walks a contiguous row range, keeps a float4
// accumulator per lane (64 lanes x 4 floats = 256-wide row), flushes to the
// collected buffer via atomicAdd only when the graph id changes (runs are long:
// avg 256 rows/graph for edges, 64 for nodes).
__device__ __forceinline__ void seg_sum_rows(const float4* __restrict__ src,
                                             const int* __restrict__ ids,
                                             float* __restrict__ dst, int col_off,
                                             int r0, int nrows) {
    const int lane = threadIdx.x & 63;
    const int wave = threadIdx.x >> 6;
    const int per_wave = nrows >> 2;
    int r = r0 + wave * per_wave;
    const int rend = r + per_wave;

    float4 acc = {0.f, 0.f, 0.f, 0.f};
    int cur = ids[r];
    for (; r < rend; ++r) {
        const int id = ids[r];
        if (id != cur) {
            float* p = dst + (size_t)cur * DIN + col_off + lane * 4;
            atomicAdd(p + 0, acc.x); atomicAdd(p + 1, acc.y);
            atomicAdd(p + 2, acc.z); atomicAdd(p + 3, acc.w);
            acc.x = acc.y = acc.z = acc.w = 0.f;
            cur = id;
        }
        const float4 v = src[(size_t)r * (D / 4) + lane];   // wave reads contiguous 1 KiB/row
        acc.x += v.x; acc.y += v.y; acc.z += v.z; acc.w += v.w;
    }
    float* p = dst + (size_t)cur * DIN + col_off + lane * 4;
    atomicAdd(p + 0, acc.x); atomicAdd(p + 1, acc.y);
    atomicAdd(p + 2, acc.z); atomicAdd(p + 3, acc.w);
}

__global__ __launch_bounds__(256) void aggregate_kernel(
        const float* __restrict__ nodes,
        const float* __restrict__ edges,
        const float* __restrict__ globals_,
        const int* __restrict__ nids,
        const int* __restrict__ eids,
        float* __restrict__ collected) {
    const int b = blockIdx.x;
    if (b < EDGE_BLOCKS) {
        seg_sum_rows((const float4*)edges, eids, collected, 0,
                     b * EDGE_CHUNK, EDGE_CHUNK);
    } else if (b < EDGE_BLOCKS + NODE_BLOCKS) {
        seg_sum_rows((const float4*)nodes, nids, collected, D,
                     (b - EDGE_BLOCKS) * NODE_CHUNK, NODE_CHUNK);
    } else {
        // copy globals into collected[:, 512:768]
        const int t = (b - EDGE_BLOCKS - NODE_BLOCKS) * 256 + threadIdx.x; // float4 idx
        const int g = t >> 6;       // graph
        const int c = t & 63;       // float4 within row
        ((float4*)collected)[(size_t)g * (DIN / 4) + (2 * D / 4) + c] =
            ((const float4*)globals_)[t];
    }
}

// Simple fp32 tiled GEMM: C[M,N] = act(A[M,K] @ B[K,N] + bias), tile 32x64,
// 256 threads (16x16), micro-tile 2x4 per thread. As padded +1 to break the
// row-stride-16 bank aliasing (4-way -> conflict-free); Bs b128 reads are
// 2-way aliased which is free on gfx950 (m136).
template <int TM, int TN, int TK>
__global__ __launch_bounds__(256) void gemm_bias_act(
        const float* __restrict__ A, const float* __restrict__ B,
        const float* __restrict__ bias, float* __restrict__ C,
        int M, int N, int K, int relu) {
    __shared__ float As[TM][TK + 1];
    __shared__ __align__(16) float Bs[TK][TN];

    const int tid = threadIdx.x;
    const int tx = tid & 15;   // -> 4 cols each
    const int ty = tid >> 4;   // -> 2 rows each
    const int m0 = blockIdx.y * TM;
    const int n0 = blockIdx.x * TN;

    float4 acc0 = {0.f, 0.f, 0.f, 0.f};
    float4 acc1 = {0.f, 0.f, 0.f, 0.f};

    for (int kt = 0; kt < K; kt += TK) {
        {   // stage A tile: 32x16 floats, float2/thread
            const int r = tid >> 3;
            const int c = (tid & 7) * 2;
            const float2 a2 = *(const float2*)&A[(size_t)(m0 + r) * K + kt + c];
            As[r][c] = a2.x; As[r][c + 1] = a2.y;
        }
        {   // stage B tile: 16x64 floats, float4/thread
            const int r = tid >> 4;
            const int c = (tid & 15) * 4;
            *(float4*)&Bs[r][c] = *(const float4*)&B[(size_t)(kt + r) * N + n0 + c];
        }
        __syncthreads();
#pragma unroll
        for (int k = 0; k < TK; ++k) {
            const float a0 = As[ty * 2 + 0][k];
            const float a1 = As[ty * 2 + 1][k];
            const float4 bv = *(const float4*)&Bs[k][tx * 4];
            acc0.x += a0 * bv.x; acc0.y += a0 * bv.y;
            acc0.z += a0 * bv.z; acc0.w += a0 * bv.w;
            acc1.x += a1 * bv.x; acc1.y += a1 * bv.y;
            acc1.z += a1 * bv.z; acc1.w += a1 * bv.w;
        }
        __syncthreads();
    }

    const int col = n0 + tx * 4;
    const int row = m0 + ty * 2;
    const float4 bv = *(const float4*)&bias[col];
    float4 o0, o1;
    o0.x = acc0.x + bv.x; o0.y = acc0.y + bv.y; o0.z = acc0.z + bv.z; o0.w = acc0.w + bv.w;
    o1.x = acc1.x + bv.x; o1.y = acc1.y + bv.y; o1.z = acc1.z + bv.z; o1.w = acc1.w + bv.w;
    if (relu) {
        o0.x = fmaxf(o0.x, 0.f); o0.y = fmaxf(o0.y, 0.f);
        o0.z = fmaxf(o0.z, 0.f); o0.w = fmaxf(o0.w, 0.f);
        o1.x = fmaxf(o1.x, 0.f); o1.y = fmaxf(o1.y, 0.f);
        o1.z = fmaxf(o1.z, 0.f); o1.w = fmaxf(o1.w, 0.f);
    }
    *(float4*)&C[(size_t)row * N + col] = o0;
    *(float4*)&C[(size_t)(row + 1) * N + col] = o1;
}

extern "C" void kernel_launch(void* const* d_in, const int* in_sizes, int n_in,
                              void* d_out, int out_size, void* d_ws, size_t ws_size,
                              hipStream_t stream) {
    const float* nodes    = (const float*)d_in[0];
    const float* edges    = (const float*)d_in[1];
    const float* globals_ = (const float*)d_in[2];
    const int*   nids     = (const int*)d_in[3];
    const int*   eids     = (const int*)d_in[4];
    const float* W1       = (const float*)d_in[5];
    const float* b1       = (const float*)d_in[6];
    const float* W2       = (const float*)d_in[7];
    const float* b2       = (const float*)d_in[8];
    float* out = (float*)d_out;

    float* collected = (float*)d_ws;                 // [G, DIN]  (3 MB)
    float* h         = collected + (size_t)G * DIN;  // [G, DHID] (2 MB)

    // zero the atomic-accumulated part of `collected` (ws is poisoned 0xAA)
    hipMemsetAsync(collected, 0, (size_t)G * DIN * sizeof(float), stream);

    aggregate_kernel<<<EDGE_BLOCKS + NODE_BLOCKS + COPY_BLOCKS, 256, 0, stream>>>(
        nodes, edges, globals_, nids, eids, collected);

    gemm_bias_act<32, 64, 16><<<dim3(DHID / 64, G / 32), 256, 0, stream>>>(
        collected, W1, b1, h, G, DHID, DIN, 1);

    gemm_bias_act<32, 64, 16><<<dim3(DOUT / 64, G / 32), 256, 0, stream>>>(
        h, W2, b2, out, G, DOUT, DHID, 0);
}

// Round 2
// 473.502 us; speedup vs baseline: 1.0807x; 1.0807x over previous
//
#include <hip/hip_runtime.h>

#define G      1024
#define NNODES 65536
#define NEDGES 262144
#define D      256
#define DIN    768
#define DHID   512
#define DOUT   256

constexpr int EDGE_CHUNK  = 128;                    // rows per block (4 waves -> 32 rows/wave)
constexpr int NODE_CHUNK  = 64;                     // 16 rows/wave
constexpr int EDGE_BLOCKS = NEDGES / EDGE_CHUNK;    // 2048
constexpr int NODE_BLOCKS = NNODES / NODE_CHUNK;    // 1024
constexpr int COPY_BLOCKS = (G * D / 4) / 256;      // 256 (float4 copy of globals)

__device__ __forceinline__ void flush_acc(float* __restrict__ dst, int col_off,
                                          int cur, int lane, float4& acc) {
    float* p = dst + (size_t)cur * DIN + col_off + lane * 4;
    atomicAdd(p + 0, acc.x); atomicAdd(p + 1, acc.y);
    atomicAdd(p + 2, acc.z); atomicAdd(p + 3, acc.w);
    acc.x = acc.y = acc.z = acc.w = 0.f;
}

// Sorted-segment sum, 8x unrolled: issue 8 independent row loads + the 8 ids
// up-front (8 KiB MLP per wave), then a run-uniform fast path (no per-row
// branch) when the whole group shares the current id. Flush via atomicAdd on
// id change only (runs avg 256 rows for edges, 64 for nodes).
__device__ __forceinline__ void seg_sum_rows(const float4* __restrict__ src,
                                             const int* __restrict__ ids,
                                             float* __restrict__ dst, int col_off,
                                             int r0, int nrows) {
    const int lane = threadIdx.x & 63;
    const int wave = threadIdx.x >> 6;
    const int per_wave = nrows >> 2;           // 32 (edges) / 16 (nodes)
    int r = r0 + wave * per_wave;
    const int rend = r + per_wave;

    float4 acc = {0.f, 0.f, 0.f, 0.f};
    int cur = ids[r];
    for (; r < rend; r += 8) {
        const int4 ia = *(const int4*)&ids[r];
        const int4 ib = *(const int4*)&ids[r + 4];
        float4 v0 = src[(size_t)(r + 0) * (D / 4) + lane];
        float4 v1 = src[(size_t)(r + 1) * (D / 4) + lane];
        float4 v2 = src[(size_t)(r + 2) * (D / 4) + lane];
        float4 v3 = src[(size_t)(r + 3) * (D / 4) + lane];
        float4 v4 = src[(size_t)(r + 4) * (D / 4) + lane];
        float4 v5 = src[(size_t)(r + 5) * (D / 4) + lane];
        float4 v6 = src[(size_t)(r + 6) * (D / 4) + lane];
        float4 v7 = src[(size_t)(r + 7) * (D / 4) + lane];
        if (ia.x == cur && ib.w == cur) {       // whole group in current run
            acc.x += v0.x + v1.x + v2.x + v3.x + v4.x + v5.x + v6.x + v7.x;
            acc.y += v0.y + v1.y + v2.y + v3.y + v4.y + v5.y + v6.y + v7.y;
            acc.z += v0.z + v1.z + v2.z + v3.z + v4.z + v5.z + v6.z + v7.z;
            acc.w += v0.w + v1.w + v2.w + v3.w + v4.w + v5.w + v6.w + v7.w;
        } else {                                // boundary group: per-row
            const int idv[8] = {ia.x, ia.y, ia.z, ia.w, ib.x, ib.y, ib.z, ib.w};
            const float4 vv[8] = {v0, v1, v2, v3, v4, v5, v6, v7};
#pragma unroll
            for (int j = 0; j < 8; ++j) {
                if (idv[j] != cur) { flush_acc(dst, col_off, cur, lane, acc); cur = idv[j]; }
                acc.x += vv[j].x; acc.y += vv[j].y; acc.z += vv[j].z; acc.w += vv[j].w;
            }
        }
    }
    flush_acc(dst, col_off, cur, lane, acc);
}

__global__ __launch_bounds__(256) void aggregate_kernel(
        const float* __restrict__ nodes,
        const float* __restrict__ edges,
        const float* __restrict__ globals_,
        const int* __restrict__ nids,
        const int* __restrict__ eids,
        float* __restrict__ collected) {
    const int b = blockIdx.x;
    if (b < EDGE_BLOCKS) {
        seg_sum_rows((const float4*)edges, eids, collected, 0,
                     b * EDGE_CHUNK, EDGE_CHUNK);
    } else if (b < EDGE_BLOCKS + NODE_BLOCKS) {
        seg_sum_rows((const float4*)nodes, nids, collected, D,
                     (b - EDGE_BLOCKS) * NODE_CHUNK, NODE_CHUNK);
    } else {
        // copy globals into collected[:, 512:768]
        const int t = (b - EDGE_BLOCKS - NODE_BLOCKS) * 256 + threadIdx.x; // float4 idx
        const int g = t >> 6;       // graph
        const int c = t & 63;       // float4 within row
        ((float4*)collected)[(size_t)g * (DIN / 4) + (2 * D / 4) + c] =
            ((const float4*)globals_)[t];
    }
}

// fp32 tiled GEMM: C[M,N] = act(A[M,K] @ B[K,N] + bias), tile 32x64, TK=32,
// 256 threads (16x16), micro-tile 2x4. As padded +1 (conflict-free scalar
// reads); Bs b128 reads are 2-way bank-aliased which is free (m136).
template <int TM, int TN, int TK>
__global__ __launch_bounds__(256) void gemm_bias_act(
        const float* __restrict__ A, const float* __restrict__ B,
        const float* __restrict__ bias, float* __restrict__ C,
        int M, int N, int K, int relu) {
    __shared__ float As[TM][TK + 1];
    __shared__ __align__(16) float Bs[TK][TN];

    const int tid = threadIdx.x;
    const int tx = tid & 15;   // 4 cols each
    const int ty = tid >> 4;   // 2 rows each
    const int m0 = blockIdx.y * TM;
    const int n0 = blockIdx.x * TN;

    float4 acc0 = {0.f, 0.f, 0.f, 0.f};
    float4 acc1 = {0.f, 0.f, 0.f, 0.f};

    for (int kt = 0; kt < K; kt += TK) {
        {   // stage A tile: 32x32 floats, one float4/thread
            const int r = tid >> 3;
            const int c = (tid & 7) * 4;
            const float4 a4 = *(const float4*)&A[(size_t)(m0 + r) * K + kt + c];
            As[r][c] = a4.x; As[r][c + 1] = a4.y; As[r][c + 2] = a4.z; As[r][c + 3] = a4.w;
        }
        {   // stage B tile: 32x64 floats, two float4/thread
            const int r = tid >> 3;
            const int c = (tid & 7) * 8;
            *(float4*)&Bs[r][c]     = *(const float4*)&B[(size_t)(kt + r) * N + n0 + c];
            *(float4*)&Bs[r][c + 4] = *(const float4*)&B[(size_t)(kt + r) * N + n0 + c + 4];
        }
        __syncthreads();
#pragma unroll
        for (int k = 0; k < TK; ++k) {
            const float a0 = As[ty * 2 + 0][k];
            const float a1 = As[ty * 2 + 1][k];
            const float4 bv = *(const float4*)&Bs[k][tx * 4];
            acc0.x += a0 * bv.x; acc0.y += a0 * bv.y;
            acc0.z += a0 * bv.z; acc0.w += a0 * bv.w;
            acc1.x += a1 * bv.x; acc1.y += a1 * bv.y;
            acc1.z += a1 * bv.z; acc1.w += a1 * bv.w;
        }
        __syncthreads();
    }

    const int col = n0 + tx * 4;
    const int row = m0 + ty * 2;
    const float4 bv = *(const float4*)&bias[col];
    float4 o0, o1;
    o0.x = acc0.x + bv.x; o0.y = acc0.y + bv.y; o0.z = acc0.z + bv.z; o0.w = acc0.w + bv.w;
    o1.x = acc1.x + bv.x; o1.y = acc1.y + bv.y; o1.z = acc1.z + bv.z; o1.w = acc1.w + bv.w;
    if (relu) {
        o0.x = fmaxf(o0.x, 0.f); o0.y = fmaxf(o0.y, 0.f);
        o0.z = fmaxf(o0.z, 0.f); o0.w = fmaxf(o0.w, 0.f);
        o1.x = fmaxf(o1.x, 0.f); o1.y = fmaxf(o1.y, 0.f);
        o1.z = fmaxf(o1.z, 0.f); o1.w = fmaxf(o1.w, 0.f);
    }
    *(float4*)&C[(size_t)row * N + col] = o0;
    *(float4*)&C[(size_t)(row + 1) * N + col] = o1;
}

extern "C" void kernel_launch(void* const* d_in, const int* in_sizes, int n_in,
                              void* d_out, int out_size, void* d_ws, size_t ws_size,
                              hipStream_t stream) {
    const float* nodes    = (const float*)d_in[0];
    const float* edges    = (const float*)d_in[1];
    const float* globals_ = (const float*)d_in[2];
    const int*   nids     = (const int*)d_in[3];
    const int*   eids     = (const int*)d_in[4];
    const float* W1       = (const float*)d_in[5];
    const float* b1       = (const float*)d_in[6];
    const float* W2       = (const float*)d_in[7];
    const float* b2       = (const float*)d_in[8];
    float* out = (float*)d_out;

    float* collected = (float*)d_ws;                 // [G, DIN]  (3 MB)
    float* h         = collected + (size_t)G * DIN;  // [G, DHID] (2 MB)

    // zero only the atomic-accumulated columns [0, 512); cols [512,768) are
    // fully overwritten by the globals copy
    hipMemsetAsync(collected, 0, (size_t)G * DIN * sizeof(float), stream);

    aggregate_kernel<<<EDGE_BLOCKS + NODE_BLOCKS + COPY_BLOCKS, 256, 0, stream>>>(
        nodes, edges, globals_, nids, eids, collected);

    gemm_bias_act<32, 64, 32><<<dim3(DHID / 64, G / 32), 256, 0, stream>>>(
        collected, W1, b1, h, G, DHID, DIN, 1);

    gemm_bias_act<32, 64, 32><<<dim3(DOUT / 64, G / 32), 256, 0, stream>>>(
        h, W2, b2, out, G, DOUT, DHID, 0);
}